// Round 6
// baseline (324.928 us; speedup 1.0000x reference)
//
#include <hip/hip_runtime.h>

#define N_NODES 100000
#define N_EDGES 3200000
#define N_GRAPHS 1024
#define HID 32
#define BN_EPS 1e-5f
#define NB 256

#define NBKT 512
#define NPB 196                 // nodes per bucket; NBKT*NPB = 100352 >= N_NODES
#define PART_TILE 4096
#define PART_THREADS 256
#define PART_EPT (PART_TILE / PART_THREADS)   // 16

// ---------------- helpers ----------------

__device__ __forceinline__ int lbound(const int* __restrict__ a, int n, int key) {
    int lo = 0, hi = n;
    while (lo < hi) {
        int mid = (lo + hi) >> 1;
        if (a[mid] < key) lo = mid + 1; else hi = mid;
    }
    return lo;
}

__device__ __forceinline__ float bf2f(unsigned short h) {
    return __uint_as_float((unsigned)h << 16);
}
__device__ __forceinline__ unsigned short f2bf(float x) {   // round-to-nearest-even
    unsigned u = __float_as_uint(x);
    u += 0x7fffu + ((u >> 16) & 1u);
    return (unsigned short)(u >> 16);
}

// ---------------- CSR build (bucketed multisplit, 4B-packed edges) ----------------

__global__ void k_zero(int* __restrict__ bhist) {
    bhist[threadIdx.x] = 0;
}

__global__ void k_hist(const int* __restrict__ dst, int* __restrict__ bhist) {
    __shared__ int h[NBKT];
    for (int i = threadIdx.x; i < NBKT; i += NB) h[i] = 0;
    __syncthreads();
    for (int e = blockIdx.x * NB + threadIdx.x; e < N_EDGES; e += gridDim.x * NB)
        atomicAdd(&h[__builtin_nontemporal_load(&dst[e]) / NPB], 1);
    __syncthreads();
    for (int i = threadIdx.x; i < NBKT; i += NB)
        if (h[i]) atomicAdd(&bhist[i], h[i]);
}

// single block of NBKT threads: exclusive scan -> bstart, bcursor
__global__ void k_scan512(const int* __restrict__ bhist, int* __restrict__ bstart,
                          int* __restrict__ bcursor) {
    __shared__ int sm[NBKT];
    int t = threadIdx.x;
    int orig = bhist[t];
    sm[t] = orig;
    __syncthreads();
    for (int off = 1; off < NBKT; off <<= 1) {
        int v = (t >= off) ? sm[t - off] : 0;
        __syncthreads();
        sm[t] += v;
        __syncthreads();
    }
    int ex = sm[t] - orig;
    bstart[t] = ex;
    bcursor[t] = ex;
    if (t == NBKT - 1) bstart[NBKT] = sm[t];
}

// partition edges into bucket-major ebuf; entry = (dst_local << 17) | src  (4B)
__global__ void k_partition(const int* __restrict__ src, const int* __restrict__ dst,
                            int* __restrict__ bcursor, unsigned* __restrict__ ebuf) {
    __shared__ int lh[NBKT];
    __shared__ int lcur[NBKT];
    const int tile0 = blockIdx.x * PART_TILE;
    for (int i = threadIdx.x; i < NBKT; i += PART_THREADS) lh[i] = 0;
    __syncthreads();
    int s[PART_EPT], bk[PART_EPT], dl[PART_EPT];
#pragma unroll
    for (int k = 0; k < PART_EPT; ++k) {
        int e = tile0 + k * PART_THREADS + threadIdx.x;
        bool ok = (e < N_EDGES);
        int sv = ok ? __builtin_nontemporal_load(&src[e]) : 0;
        int dv = ok ? __builtin_nontemporal_load(&dst[e]) : 0;
        s[k] = sv;
        bk[k] = ok ? (dv / NPB) : -1;
        dl[k] = dv - bk[k] * NPB;
        if (ok) atomicAdd(&lh[bk[k]], 1);
    }
    __syncthreads();
    for (int i = threadIdx.x; i < NBKT; i += PART_THREADS)
        lcur[i] = lh[i] ? atomicAdd(&bcursor[i], lh[i]) : 0;
    __syncthreads();
#pragma unroll
    for (int k = 0; k < PART_EPT; ++k) {
        if (bk[k] >= 0) {
            int pos = atomicAdd(&lcur[bk[k]], 1);
            ebuf[pos] = ((unsigned)dl[k] << 17) | (unsigned)s[k];
        }
    }
}

// per-bucket: node histogram -> rowstart/deg/dinv/zs1, then scatter csr
__global__ void k_bucket(const int* __restrict__ bstart,
                         const unsigned* __restrict__ ebuf,
                         const float* __restrict__ x,
                         int* __restrict__ rowstart, int* __restrict__ deg,
                         float* __restrict__ dinv, float* __restrict__ zs1,
                         int* __restrict__ csr) {
    __shared__ int hist[NPB];
    __shared__ int sm[256];
    __shared__ int lcur[NPB];
    const int b = blockIdx.x;
    const int node0 = b * NPB;
    const int nn = N_NODES - node0;
    const int elo = bstart[b], ehi = bstart[b + 1];
    const int t = threadIdx.x;

    for (int i = t; i < NPB; i += blockDim.x) hist[i] = 0;
    __syncthreads();
    for (int e = elo + t; e < ehi; e += blockDim.x)
        atomicAdd(&hist[ebuf[e] >> 17], 1);
    __syncthreads();
    int orig = 0;
    if (t < 256) { orig = (t < NPB) ? hist[t] : 0; sm[t] = orig; }
    __syncthreads();
    for (int off = 1; off < 256; off <<= 1) {
        int v = 0;
        if (t < 256 && t >= off) v = sm[t - off];
        __syncthreads();
        if (t < 256) sm[t] += v;
        __syncthreads();
    }
    if (t < NPB) {
        int ex = sm[t] - orig;
        lcur[t] = ex;
        if (t < nn) {
            int node = node0 + t;
            rowstart[node] = elo + ex;
            deg[node] = orig;
            float di = rsqrtf((float)(orig + 1));
            dinv[node] = di;
            zs1[node] = di * x[node];
        }
    }
    __syncthreads();
    for (int e = elo + t; e < ehi; e += blockDim.x) {
        unsigned pk = ebuf[e];
        int pos = atomicAdd(&lcur[pk >> 17], 1);
        csr[elo + pos] = (int)(pk & 0x1FFFFu);
    }
}

// ---------------- layer 1: scalar gather -> sd = (s, dinv) ----------------

__global__ void k_gather1(const int* __restrict__ rowstart, const int* __restrict__ deg,
                          const int* __restrict__ csr, const float* __restrict__ dinv,
                          const float* __restrict__ zs1, float2* __restrict__ sd) {
    int v = blockIdx.x * NB + threadIdx.x;
    if (v < N_NODES) {
        int lo = rowstart[v], n = deg[v];
        float acc = zs1[v];
        int j = 0;
        for (; j + 4 <= n; j += 4) {
            int u0 = __builtin_nontemporal_load(&csr[lo + j]);
            int u1 = __builtin_nontemporal_load(&csr[lo + j + 1]);
            int u2 = __builtin_nontemporal_load(&csr[lo + j + 2]);
            int u3 = __builtin_nontemporal_load(&csr[lo + j + 3]);
            float a0 = zs1[u0], a1 = zs1[u1], a2 = zs1[u2], a3 = zs1[u3];
            acc += (a0 + a1) + (a2 + a3);
        }
        for (; j < n; ++j) acc += zs1[csr[lo + j]];
        float di = dinv[v];
        sd[v] = make_float2(di * acc, di);
    }
}

// ---------------- layer 2: wave-per-node, shfl outer-product ----------------
// zs2[u,f] = d_u*relu(s_u*A[f]+B[f]);  A = W1*scale1, B = (b1-m1)*scale1+bb1
// agg2[v,f] = d_v*( d_v*relu(s_v*A+B) + sum_u d_u*relu(s_u*A+B) )
// then h = agg2 @ W2 (via shfl), bn2+relu, prescale by d_v, store bf16.
__global__ void k_gather2(const int* __restrict__ rowstart, const int* __restrict__ deg,
                          const int* __restrict__ csr, const float2* __restrict__ sd,
                          const float* __restrict__ W1, const float* __restrict__ b1,
                          const float* __restrict__ g1, const float* __restrict__ bb1,
                          const float* __restrict__ m1, const float* __restrict__ v1,
                          const float* __restrict__ W2,
                          const float* __restrict__ b2, const float* __restrict__ g2,
                          const float* __restrict__ bb2, const float* __restrict__ m2,
                          const float* __restrict__ v2, unsigned short* __restrict__ zs3h) {
    __shared__ float Ws[HID * HID];
    for (int k = threadIdx.x; k < HID * HID; k += NB) Ws[k] = W2[k];
    __syncthreads();

    const int lane = threadIdx.x & 63;
    const int f = lane & 31;
    const int hbase = lane & 32;            // 0 for half 0, 32 for half 1
    const int v = (blockIdx.x * NB + threadIdx.x) >> 6;   // wave id = node
    if (v >= N_NODES) return;

    const float sc1 = g1[f] * rsqrtf(v1[f] + BN_EPS);
    const float A = W1[f] * sc1;
    const float Bc = (b1[f] - m1[f]) * sc1 + bb1[f];

    const float2 pv = sd[v];
    const float di = pv.y;
    const int lo = rowstart[v], n = deg[v];

    float acc = 0.0f;
    for (int base = 0; base < n; base += 64) {
        int j = base + lane;
        float s_l = 0.0f, d_l = 0.0f;
        if (j < n) {
            int u = __builtin_nontemporal_load(&csr[lo + j]);
            float2 p = sd[u];
            s_l = p.x; d_l = p.y;
        }
#pragma unroll
        for (int k = 0; k < 32; ++k) {
            float sk = __shfl(s_l, hbase + k, 64);
            float dk = __shfl(d_l, hbase + k, 64);
            acc += dk * fmaxf(sk * A + Bc, 0.0f);
        }
    }
    acc += __shfl_xor(acc, 32, 64);                        // combine the two halves
    acc = di * (acc + di * fmaxf(pv.x * A + Bc, 0.0f));    // + self term, prescale

    // matmul row (in-register, duplicated across halves) with W2 column f
    float h = b2[f];
#pragma unroll
    for (int k = 0; k < 32; ++k) {
        float rk = __shfl(acc, hbase + k, 64);
        h += rk * Ws[k * HID + f];
    }
    float sc2 = g2[f] * rsqrtf(v2[f] + BN_EPS);
    float z = fmaxf((h - m2[f]) * sc2 + bb2[f], 0.0f);
    if (lane < 32) zs3h[v * HID + f] = f2bf(di * z);
}

// ---------------- layer 3: bf16-row gather ----------------

__global__ void k_gather3(const int* __restrict__ rowstart, const int* __restrict__ deg,
                          const int* __restrict__ csr, const float* __restrict__ dinv,
                          const unsigned short* __restrict__ zs3h,
                          unsigned short* __restrict__ agg3h) {
    int t = blockIdx.x * NB + threadIdx.x;
    int v = t >> 5, f = t & 31;
    if (v < N_NODES) {
        int lo = rowstart[v], n = deg[v];
        float acc = bf2f(zs3h[v * HID + f]);
        int j = 0;
        for (; j + 8 <= n; j += 8) {
            int u0 = __builtin_nontemporal_load(&csr[lo + j]);
            int u1 = __builtin_nontemporal_load(&csr[lo + j + 1]);
            int u2 = __builtin_nontemporal_load(&csr[lo + j + 2]);
            int u3 = __builtin_nontemporal_load(&csr[lo + j + 3]);
            int u4 = __builtin_nontemporal_load(&csr[lo + j + 4]);
            int u5 = __builtin_nontemporal_load(&csr[lo + j + 5]);
            int u6 = __builtin_nontemporal_load(&csr[lo + j + 6]);
            int u7 = __builtin_nontemporal_load(&csr[lo + j + 7]);
            float a0 = bf2f(zs3h[u0 * HID + f]);
            float a1 = bf2f(zs3h[u1 * HID + f]);
            float a2 = bf2f(zs3h[u2 * HID + f]);
            float a3 = bf2f(zs3h[u3 * HID + f]);
            float a4 = bf2f(zs3h[u4 * HID + f]);
            float a5 = bf2f(zs3h[u5 * HID + f]);
            float a6 = bf2f(zs3h[u6 * HID + f]);
            float a7 = bf2f(zs3h[u7 * HID + f]);
            acc += ((a0 + a1) + (a2 + a3)) + ((a4 + a5) + (a6 + a7));
        }
        for (; j < n; ++j) acc += bf2f(zs3h[csr[lo + j] * HID + f]);
        __builtin_nontemporal_store(f2bf(dinv[v] * acc), &agg3h[v * HID + f]);
    }
}

// ---------------- pool: block per graph, mean then matmul W3 ----------------

__global__ void k_pool(const unsigned short* __restrict__ agg3h,
                       const int* __restrict__ batch,
                       const float* __restrict__ W3, const float* __restrict__ b3,
                       float* __restrict__ out) {
    __shared__ float Ws[HID * HID];
    __shared__ float part[NB / HID][HID + 1];
    __shared__ float mrow[HID];
    int g = blockIdx.x;
    for (int k = threadIdx.x; k < HID * HID; k += NB) Ws[k] = W3[k];

    int lo = lbound(batch, N_NODES, g);
    int hi = lbound(batch, N_NODES, g + 1);

    int r = threadIdx.x >> 5, f = threadIdx.x & 31;
    float acc = 0.0f;
    for (int i = lo + r; i < hi; i += NB / HID)
        acc += bf2f(__builtin_nontemporal_load(&agg3h[i * HID + f]));
    part[r][f] = acc;
    __syncthreads();
    if (threadIdx.x < HID) {
        float srow = 0.0f;
#pragma unroll
        for (int k = 0; k < NB / HID; ++k) srow += part[k][threadIdx.x];
        float c = (float)(hi - lo);
        mrow[threadIdx.x] = (hi > lo) ? srow / c : 0.0f;
    }
    __syncthreads();
    if (threadIdx.x < HID) {
        int ff = threadIdx.x;
        float o = 0.0f;
        if (hi > lo) {
            o = b3[ff];
#pragma unroll
            for (int k = 0; k < HID; ++k) o += mrow[k] * Ws[k * HID + ff];
        }
        out[g * HID + ff] = o;
    }
}

// ---------------- launch ----------------

extern "C" void kernel_launch(void* const* d_in, const int* in_sizes, int n_in,
                              void* d_out, int out_size, void* d_ws, size_t ws_size,
                              hipStream_t stream) {
    const float* x     = (const float*)d_in[0];
    const int*   eidx  = (const int*)d_in[1];     // [2, E]: row0 = src, row1 = dst
    const int*   batch = (const int*)d_in[2];
    const float* W1    = (const float*)d_in[3];
    const float* b1    = (const float*)d_in[4];
    const float* bn1g  = (const float*)d_in[5];
    const float* bn1b  = (const float*)d_in[6];
    const float* bn1m  = (const float*)d_in[7];
    const float* bn1v  = (const float*)d_in[8];
    const float* W2    = (const float*)d_in[9];
    const float* b2    = (const float*)d_in[10];
    const float* bn2g  = (const float*)d_in[11];
    const float* bn2b  = (const float*)d_in[12];
    const float* bn2m  = (const float*)d_in[13];
    const float* bn2v  = (const float*)d_in[14];
    const float* W3    = (const float*)d_in[15];
    const float* b3    = (const float*)d_in[16];
    float* out = (float*)d_out;

    const int* src = eidx;
    const int* dst = eidx + N_EDGES;

    // workspace carving (256B aligned)
    char* ws = (char*)d_ws;
    size_t off = 0;
    auto carve = [&](size_t bytes) {
        void* p = ws + off;
        off += (bytes + 255) & ~size_t(255);
        return p;
    };
    int*    bhist    = (int*)carve(NBKT * 4);
    int*    bstart   = (int*)carve((NBKT + 1) * 4);
    int*    bcursor  = (int*)carve(NBKT * 4);
    int*    rowstart = (int*)carve(N_NODES * 4);
    int*    deg      = (int*)carve(N_NODES * 4);
    float*  dinv     = (float*)carve(N_NODES * 4);
    float*  zs1      = (float*)carve(N_NODES * 4);
    float2* sd       = (float2*)carve((size_t)N_NODES * 8);        // 0.8 MB (L2-resident)
    int*    csr      = (int*)carve((size_t)N_EDGES * 4);           // 12.8 MB
    // 12.8 MB region: ebuf dead after k_bucket; then zs3h(6.4) | agg3h(6.4)
    char*   region   = (char*)carve((size_t)N_EDGES * 4);
    unsigned*       ebuf  = (unsigned*)region;
    unsigned short* zs3h  = (unsigned short*)region;
    unsigned short* agg3h = (unsigned short*)(region + (size_t)N_NODES * HID * 2);

    const int gN    = (N_NODES + NB - 1) / NB;            // 391
    const int gNF   = (N_NODES * HID + NB - 1) / NB;      // 12500
    const int gW    = ((size_t)N_NODES * 64 + NB - 1) / NB;   // 25000 (wave-per-node)
    const int gPart = (N_EDGES + PART_TILE - 1) / PART_TILE;  // 782

    k_zero<<<1, NBKT, 0, stream>>>(bhist);
    k_hist<<<1024, NB, 0, stream>>>(dst, bhist);
    k_scan512<<<1, NBKT, 0, stream>>>(bhist, bstart, bcursor);
    k_partition<<<gPart, PART_THREADS, 0, stream>>>(src, dst, bcursor, ebuf);
    k_bucket<<<NBKT, 512, 0, stream>>>(bstart, ebuf, x, rowstart, deg, dinv, zs1, csr);
    k_gather1<<<gN, NB, 0, stream>>>(rowstart, deg, csr, dinv, zs1, sd);
    k_gather2<<<gW, NB, 0, stream>>>(rowstart, deg, csr, sd,
                                     W1, b1, bn1g, bn1b, bn1m, bn1v,
                                     W2, b2, bn2g, bn2b, bn2m, bn2v, zs3h);
    k_gather3<<<gNF, NB, 0, stream>>>(rowstart, deg, csr, dinv, zs3h, agg3h);
    k_pool<<<N_GRAPHS, NB, 0, stream>>>(agg3h, batch, W3, b3, out);
}

// Round 7
// 267.421 us; speedup vs baseline: 1.2150x; 1.2150x over previous
//
#include <hip/hip_runtime.h>

#define N_NODES 100000
#define N_EDGES 3200000
#define N_GRAPHS 1024
#define HID 32
#define BN_EPS 1e-5f
#define NB 256

#define NBKT 512
#define NPB 196                 // nodes per bucket; NBKT*NPB = 100352 >= N_NODES
#define PART_TILE 4096
#define PART_THREADS 256
#define PART_EPT (PART_TILE / PART_THREADS)   // 16

#define G2_NODES 8
#define G2_WCAP 2048            // staged edges per window (16 KB LDS)

// ---------------- helpers ----------------

__device__ __forceinline__ int lbound(const int* __restrict__ a, int n, int key) {
    int lo = 0, hi = n;
    while (lo < hi) {
        int mid = (lo + hi) >> 1;
        if (a[mid] < key) lo = mid + 1; else hi = mid;
    }
    return lo;
}

__device__ __forceinline__ float bf2f(unsigned short h) {
    return __uint_as_float((unsigned)h << 16);
}
__device__ __forceinline__ unsigned short f2bf(float x) {   // round-to-nearest-even
    unsigned u = __float_as_uint(x);
    u += 0x7fffu + ((u >> 16) & 1u);
    return (unsigned short)(u >> 16);
}

// ---------------- CSR build (bucketed multisplit, 4B-packed edges) ----------------

__global__ void k_zero(int* __restrict__ bhist) {
    bhist[threadIdx.x] = 0;
}

__global__ void k_hist(const int* __restrict__ dst, int* __restrict__ bhist) {
    __shared__ int h[NBKT];
    for (int i = threadIdx.x; i < NBKT; i += NB) h[i] = 0;
    __syncthreads();
    for (int e = blockIdx.x * NB + threadIdx.x; e < N_EDGES; e += gridDim.x * NB)
        atomicAdd(&h[__builtin_nontemporal_load(&dst[e]) / NPB], 1);
    __syncthreads();
    for (int i = threadIdx.x; i < NBKT; i += NB)
        if (h[i]) atomicAdd(&bhist[i], h[i]);
}

// single block of NBKT threads: exclusive scan -> bstart, bcursor
__global__ void k_scan512(const int* __restrict__ bhist, int* __restrict__ bstart,
                          int* __restrict__ bcursor) {
    __shared__ int sm[NBKT];
    int t = threadIdx.x;
    int orig = bhist[t];
    sm[t] = orig;
    __syncthreads();
    for (int off = 1; off < NBKT; off <<= 1) {
        int v = (t >= off) ? sm[t - off] : 0;
        __syncthreads();
        sm[t] += v;
        __syncthreads();
    }
    int ex = sm[t] - orig;
    bstart[t] = ex;
    bcursor[t] = ex;
    if (t == NBKT - 1) bstart[NBKT] = sm[t];
}

// partition edges into bucket-major ebuf; entry = (dst_local << 17) | src  (4B)
__global__ void k_partition(const int* __restrict__ src, const int* __restrict__ dst,
                            int* __restrict__ bcursor, unsigned* __restrict__ ebuf) {
    __shared__ int lh[NBKT];
    __shared__ int lcur[NBKT];
    const int tile0 = blockIdx.x * PART_TILE;
    for (int i = threadIdx.x; i < NBKT; i += PART_THREADS) lh[i] = 0;
    __syncthreads();
    int s[PART_EPT], bk[PART_EPT], dl[PART_EPT];
#pragma unroll
    for (int k = 0; k < PART_EPT; ++k) {
        int e = tile0 + k * PART_THREADS + threadIdx.x;
        bool ok = (e < N_EDGES);
        int sv = ok ? __builtin_nontemporal_load(&src[e]) : 0;
        int dv = ok ? __builtin_nontemporal_load(&dst[e]) : 0;
        s[k] = sv;
        bk[k] = ok ? (dv / NPB) : -1;
        dl[k] = dv - bk[k] * NPB;
        if (ok) atomicAdd(&lh[bk[k]], 1);
    }
    __syncthreads();
    for (int i = threadIdx.x; i < NBKT; i += PART_THREADS)
        lcur[i] = lh[i] ? atomicAdd(&bcursor[i], lh[i]) : 0;
    __syncthreads();
#pragma unroll
    for (int k = 0; k < PART_EPT; ++k) {
        if (bk[k] >= 0) {
            int pos = atomicAdd(&lcur[bk[k]], 1);
            ebuf[pos] = ((unsigned)dl[k] << 17) | (unsigned)s[k];
        }
    }
}

// per-bucket: node histogram -> rowstart/deg/dinv/zs1, then scatter csr
__global__ void k_bucket(const int* __restrict__ bstart,
                         const unsigned* __restrict__ ebuf,
                         const float* __restrict__ x,
                         int* __restrict__ rowstart, int* __restrict__ deg,
                         float* __restrict__ dinv, float* __restrict__ zs1,
                         int* __restrict__ csr) {
    __shared__ int hist[NPB];
    __shared__ int sm[256];
    __shared__ int lcur[NPB];
    const int b = blockIdx.x;
    const int node0 = b * NPB;
    const int nn = N_NODES - node0;
    const int elo = bstart[b], ehi = bstart[b + 1];
    const int t = threadIdx.x;

    for (int i = t; i < NPB; i += blockDim.x) hist[i] = 0;
    __syncthreads();
    for (int e = elo + t; e < ehi; e += blockDim.x)
        atomicAdd(&hist[ebuf[e] >> 17], 1);
    __syncthreads();
    int orig = 0;
    if (t < 256) { orig = (t < NPB) ? hist[t] : 0; sm[t] = orig; }
    __syncthreads();
    for (int off = 1; off < 256; off <<= 1) {
        int v = 0;
        if (t < 256 && t >= off) v = sm[t - off];
        __syncthreads();
        if (t < 256) sm[t] += v;
        __syncthreads();
    }
    if (t < NPB) {
        int ex = sm[t] - orig;
        lcur[t] = ex;
        if (t < nn) {
            int node = node0 + t;
            rowstart[node] = elo + ex;
            deg[node] = orig;
            float di = rsqrtf((float)(orig + 1));
            dinv[node] = di;
            zs1[node] = di * x[node];
        }
    }
    __syncthreads();
    for (int e = elo + t; e < ehi; e += blockDim.x) {
        unsigned pk = ebuf[e];
        int pos = atomicAdd(&lcur[pk >> 17], 1);
        csr[elo + pos] = (int)(pk & 0x1FFFFu);
    }
}

// ---------------- layer 1: scalar gather -> sd = (s, dinv) ----------------

__global__ void k_gather1(const int* __restrict__ rowstart, const int* __restrict__ deg,
                          const int* __restrict__ csr, const float* __restrict__ dinv,
                          const float* __restrict__ zs1, float2* __restrict__ sd) {
    int v = blockIdx.x * NB + threadIdx.x;
    if (v < N_NODES) {
        int lo = rowstart[v], n = deg[v];
        float acc = zs1[v];
        int j = 0;
        for (; j + 4 <= n; j += 4) {
            int u0 = __builtin_nontemporal_load(&csr[lo + j]);
            int u1 = __builtin_nontemporal_load(&csr[lo + j + 1]);
            int u2 = __builtin_nontemporal_load(&csr[lo + j + 2]);
            int u3 = __builtin_nontemporal_load(&csr[lo + j + 3]);
            float a0 = zs1[u0], a1 = zs1[u1], a2 = zs1[u2], a3 = zs1[u3];
            acc += (a0 + a1) + (a2 + a3);
        }
        for (; j < n; ++j) acc += zs1[csr[lo + j]];
        float di = dinv[v];
        sd[v] = make_float2(di * acc, di);
    }
}

// ---------------- layer 2: LDS-staged rank-1 gather ----------------
// Block = 8 nodes; block's edges contiguous in CSR. Stage sd[csr[...]] into
// LDS once (1 random 8B L2-hit per edge), then 32 feature-lanes per node
// consume from LDS broadcast. zs2[u,f] = d_u*relu(s_u*A[f]+B[f]).
__global__ void k_gather2(const int* __restrict__ rowstart, const int* __restrict__ deg,
                          const int* __restrict__ csr, const float2* __restrict__ sd,
                          const float* __restrict__ W1, const float* __restrict__ b1,
                          const float* __restrict__ g1, const float* __restrict__ bb1,
                          const float* __restrict__ m1, const float* __restrict__ v1,
                          const float* __restrict__ W2,
                          const float* __restrict__ b2, const float* __restrict__ g2,
                          const float* __restrict__ bb2, const float* __restrict__ m2,
                          const float* __restrict__ v2,
                          unsigned short* __restrict__ zs3a,
                          unsigned short* __restrict__ zs3b) {
    __shared__ float Ws[HID * HID];
    __shared__ float2 sde[G2_WCAP];
    __shared__ float rowbuf[G2_NODES][HID + 1];
    __shared__ int sb[2];
    const int tid = threadIdx.x;
    for (int k = tid; k < HID * HID; k += NB) Ws[k] = W2[k];

    const int r = tid >> 5, f = tid & 31;
    const int v = blockIdx.x * G2_NODES + r;
    const bool valid = v < N_NODES;

    if (tid == 0) {
        int first = blockIdx.x * G2_NODES;
        int last = min(first + G2_NODES - 1, N_NODES - 1);
        sb[0] = rowstart[first];
        sb[1] = rowstart[last] + deg[last];
    }

    const float sc1 = g1[f] * rsqrtf(v1[f] + BN_EPS);
    const float A = W1[f] * sc1;
    const float Bc = (b1[f] - m1[f]) * sc1 + bb1[f];

    float di = 0.0f, acc = 0.0f;
    int rs = 0, re = 0;
    if (valid) {
        rs = rowstart[v];
        re = rs + deg[v];
        float2 pv = sd[v];
        di = pv.y;
        acc = di * fmaxf(pv.x * A + Bc, 0.0f);   // self-loop term zs2[v]
    }
    __syncthreads();
    const int blo = sb[0], bhi = sb[1];

    for (int w = blo; w < bhi; w += G2_WCAP) {
        const int wn = min(G2_WCAP, bhi - w);
        for (int i = tid; i < wn; i += NB) {
            int u = __builtin_nontemporal_load(&csr[w + i]);
            sde[i] = sd[u];
        }
        __syncthreads();
        int jlo = max(rs, w) - w;
        int jhi = min(re, w + wn) - w;
        int j = jlo;
        for (; j + 4 <= jhi; j += 4) {
            float2 p0 = sde[j], p1 = sde[j + 1], p2 = sde[j + 2], p3 = sde[j + 3];
            float a0 = p0.y * fmaxf(p0.x * A + Bc, 0.0f);
            float a1 = p1.y * fmaxf(p1.x * A + Bc, 0.0f);
            float a2 = p2.y * fmaxf(p2.x * A + Bc, 0.0f);
            float a3 = p3.y * fmaxf(p3.x * A + Bc, 0.0f);
            acc += (a0 + a1) + (a2 + a3);
        }
        for (; j < jhi; ++j) {
            float2 p = sde[j];
            acc += p.y * fmaxf(p.x * A + Bc, 0.0f);
        }
        __syncthreads();
    }
    acc *= di;                 // agg2[v,f]
    rowbuf[r][f] = acc;
    __syncthreads();
    if (valid) {
        float h = b2[f];
#pragma unroll
        for (int k = 0; k < HID; ++k) h += rowbuf[r][k] * Ws[k * HID + f];
        float sc2 = g2[f] * rsqrtf(v2[f] + BN_EPS);
        float z = fmaxf((h - m2[f]) * sc2 + bb2[f], 0.0f);
        unsigned short o = f2bf(di * z);
        if (f < 16) zs3a[v * 16 + f] = o;
        else        zs3b[v * 16 + (f - 16)] = o;
    }
}

// ---------------- layer 3: half-feature gather (3.2MB table, L2-resident) ----------------

__global__ void k_gather3h(const int* __restrict__ rowstart, const int* __restrict__ deg,
                           const int* __restrict__ csr, const float* __restrict__ dinv,
                           const unsigned short* __restrict__ tab,   // [N][16]
                           unsigned short* __restrict__ agg3h, int halfofs) {
    int t = blockIdx.x * NB + threadIdx.x;
    int v = t >> 4, f = t & 15;
    if (v < N_NODES) {
        int lo = rowstart[v], n = deg[v];
        float acc = bf2f(tab[v * 16 + f]);
        int j = 0;
        for (; j + 8 <= n; j += 8) {
            int u0 = __builtin_nontemporal_load(&csr[lo + j]);
            int u1 = __builtin_nontemporal_load(&csr[lo + j + 1]);
            int u2 = __builtin_nontemporal_load(&csr[lo + j + 2]);
            int u3 = __builtin_nontemporal_load(&csr[lo + j + 3]);
            int u4 = __builtin_nontemporal_load(&csr[lo + j + 4]);
            int u5 = __builtin_nontemporal_load(&csr[lo + j + 5]);
            int u6 = __builtin_nontemporal_load(&csr[lo + j + 6]);
            int u7 = __builtin_nontemporal_load(&csr[lo + j + 7]);
            float a0 = bf2f(tab[u0 * 16 + f]);
            float a1 = bf2f(tab[u1 * 16 + f]);
            float a2 = bf2f(tab[u2 * 16 + f]);
            float a3 = bf2f(tab[u3 * 16 + f]);
            float a4 = bf2f(tab[u4 * 16 + f]);
            float a5 = bf2f(tab[u5 * 16 + f]);
            float a6 = bf2f(tab[u6 * 16 + f]);
            float a7 = bf2f(tab[u7 * 16 + f]);
            acc += ((a0 + a1) + (a2 + a3)) + ((a4 + a5) + (a6 + a7));
        }
        for (; j < n; ++j) acc += bf2f(tab[csr[lo + j] * 16 + f]);
        __builtin_nontemporal_store(f2bf(dinv[v] * acc), &agg3h[v * HID + halfofs + f]);
    }
}

// ---------------- pool: block per graph, mean then matmul W3 ----------------

__global__ void k_pool(const unsigned short* __restrict__ agg3h,
                       const int* __restrict__ batch,
                       const float* __restrict__ W3, const float* __restrict__ b3,
                       float* __restrict__ out) {
    __shared__ float Ws[HID * HID];
    __shared__ float part[NB / HID][HID + 1];
    __shared__ float mrow[HID];
    int g = blockIdx.x;
    for (int k = threadIdx.x; k < HID * HID; k += NB) Ws[k] = W3[k];

    int lo = lbound(batch, N_NODES, g);
    int hi = lbound(batch, N_NODES, g + 1);

    int r = threadIdx.x >> 5, f = threadIdx.x & 31;
    float acc = 0.0f;
    for (int i = lo + r; i < hi; i += NB / HID)
        acc += bf2f(__builtin_nontemporal_load(&agg3h[i * HID + f]));
    part[r][f] = acc;
    __syncthreads();
    if (threadIdx.x < HID) {
        float srow = 0.0f;
#pragma unroll
        for (int k = 0; k < NB / HID; ++k) srow += part[k][threadIdx.x];
        float c = (float)(hi - lo);
        mrow[threadIdx.x] = (hi > lo) ? srow / c : 0.0f;
    }
    __syncthreads();
    if (threadIdx.x < HID) {
        int ff = threadIdx.x;
        float o = 0.0f;
        if (hi > lo) {
            o = b3[ff];
#pragma unroll
            for (int k = 0; k < HID; ++k) o += mrow[k] * Ws[k * HID + ff];
        }
        out[g * HID + ff] = o;
    }
}

// ---------------- launch ----------------

extern "C" void kernel_launch(void* const* d_in, const int* in_sizes, int n_in,
                              void* d_out, int out_size, void* d_ws, size_t ws_size,
                              hipStream_t stream) {
    const float* x     = (const float*)d_in[0];
    const int*   eidx  = (const int*)d_in[1];     // [2, E]: row0 = src, row1 = dst
    const int*   batch = (const int*)d_in[2];
    const float* W1    = (const float*)d_in[3];
    const float* b1    = (const float*)d_in[4];
    const float* bn1g  = (const float*)d_in[5];
    const float* bn1b  = (const float*)d_in[6];
    const float* bn1m  = (const float*)d_in[7];
    const float* bn1v  = (const float*)d_in[8];
    const float* W2    = (const float*)d_in[9];
    const float* b2    = (const float*)d_in[10];
    const float* bn2g  = (const float*)d_in[11];
    const float* bn2b  = (const float*)d_in[12];
    const float* bn2m  = (const float*)d_in[13];
    const float* bn2v  = (const float*)d_in[14];
    const float* W3    = (const float*)d_in[15];
    const float* b3    = (const float*)d_in[16];
    float* out = (float*)d_out;

    const int* src = eidx;
    const int* dst = eidx + N_EDGES;

    // workspace carving (256B aligned)
    char* ws = (char*)d_ws;
    size_t off = 0;
    auto carve = [&](size_t bytes) {
        void* p = ws + off;
        off += (bytes + 255) & ~size_t(255);
        return p;
    };
    int*    bhist    = (int*)carve(NBKT * 4);
    int*    bstart   = (int*)carve((NBKT + 1) * 4);
    int*    bcursor  = (int*)carve(NBKT * 4);
    int*    rowstart = (int*)carve(N_NODES * 4);
    int*    deg      = (int*)carve(N_NODES * 4);
    float*  dinv     = (float*)carve(N_NODES * 4);
    float*  zs1      = (float*)carve(N_NODES * 4);
    float2* sd       = (float2*)carve((size_t)N_NODES * 8);        // 0.8 MB (L2-resident)
    int*    csr      = (int*)carve((size_t)N_EDGES * 4);           // 12.8 MB
    // 12.8 MB region: ebuf dead after k_bucket; then zs3a(3.2) | zs3b(3.2) | agg3h(6.4)
    char*   region   = (char*)carve((size_t)N_EDGES * 4);
    unsigned*       ebuf  = (unsigned*)region;
    unsigned short* zs3a  = (unsigned short*)region;
    unsigned short* zs3b  = (unsigned short*)(region + (size_t)N_NODES * 16 * 2);
    unsigned short* agg3h = (unsigned short*)(region + (size_t)N_NODES * 32 * 2);

    const int gN    = (N_NODES + NB - 1) / NB;                 // 391
    const int gG2   = (N_NODES + G2_NODES - 1) / G2_NODES;     // 12500
    const int gG3   = (N_NODES * 16 + NB - 1) / NB;            // 6250
    const int gPart = (N_EDGES + PART_TILE - 1) / PART_TILE;   // 782

    k_zero<<<1, NBKT, 0, stream>>>(bhist);
    k_hist<<<1024, NB, 0, stream>>>(dst, bhist);
    k_scan512<<<1, NBKT, 0, stream>>>(bhist, bstart, bcursor);
    k_partition<<<gPart, PART_THREADS, 0, stream>>>(src, dst, bcursor, ebuf);
    k_bucket<<<NBKT, 512, 0, stream>>>(bstart, ebuf, x, rowstart, deg, dinv, zs1, csr);
    k_gather1<<<gN, NB, 0, stream>>>(rowstart, deg, csr, dinv, zs1, sd);
    k_gather2<<<gG2, NB, 0, stream>>>(rowstart, deg, csr, sd,
                                      W1, b1, bn1g, bn1b, bn1m, bn1v,
                                      W2, b2, bn2g, bn2b, bn2m, bn2v, zs3a, zs3b);
    k_gather3h<<<gG3, NB, 0, stream>>>(rowstart, deg, csr, dinv, zs3a, agg3h, 0);
    k_gather3h<<<gG3, NB, 0, stream>>>(rowstart, deg, csr, dinv, zs3b, agg3h, 16);
    k_pool<<<N_GRAPHS, NB, 0, stream>>>(agg3h, batch, W3, b3, out);
}